// Round 7
// baseline (225.274 us; speedup 1.0000x reference)
//
#include <hip/hip_runtime.h>
#include <math.h>

typedef unsigned int uint32;
typedef __attribute__((ext_vector_type(8))) short short8;   // bf16x8 MFMA frag
typedef __attribute__((ext_vector_type(4))) float f32x4;    // MFMA acc

#define NEG_SLOPE 0.2f
#define EPSV 1e-5f
#define BSHIFT 9                 // 512 nodes per bucket
#define BCAP 10240               // per-bucket edge capacity (avg ~8192)
#define CHUNK 8192               // edges per block in bucket_scatter (512 thr x 16)

__device__ __forceinline__ unsigned short f2bf(float v) {
    unsigned u = __float_as_uint(v);
    unsigned r = (u + 0x7fffu + ((u >> 16) & 1u)) >> 16;   // RNE
    return (unsigned short)r;
}
__device__ __forceinline__ float bflo(uint32 p) { return __uint_as_float(p << 16); }
__device__ __forceinline__ float bfhi(uint32 p) { return __uint_as_float(p & 0xffff0000u); }

// ---------------- Prep: W (f32 [k][n]) -> Wtb (bf16 [n][k]) once ----------------
__global__ __launch_bounds__(256) void prep_w_kernel(const float* __restrict__ W,
                                                     unsigned short* __restrict__ Wtb) {
    int tid = threadIdx.x;
#pragma unroll
    for (int it = 0; it < 64; ++it) {
        int o = it * 256 + tid;          // o = n*128 + k
        int n = o >> 7, k = o & 127;
        Wtb[o] = f2bf(W[k * 128 + n]);
    }
}

// ---------------- Kernel A: feat = x @ W via MFMA bf16, fused el/er ----------------
// Block: 256 thr (4 waves), 64 rows x 128 cols, K=128.
// LDS: Wt[n][k] (bf16, pad 136) + xb[r][k] (bf16, pad 136) = 52KB.
__global__ __launch_bounds__(256) void gemm_feat_kernel(
    const float* __restrict__ x, const unsigned short* __restrict__ Wtb,
    const float* __restrict__ attn_l, const float* __restrict__ attn_r,
    uint4* __restrict__ featb4, float* __restrict__ el, float* __restrict__ er,
    int N)
{
    __shared__ unsigned short Wt[128 * 136];
    __shared__ unsigned short xb[64 * 136];

    const int tid = threadIdx.x;
    const int r0  = blockIdx.x * 64;

    // stage Wt[n][k] from pre-converted bf16 W^T: coalesced uint4 loads
#pragma unroll
    for (int it = 0; it < 8; ++it) {
        int o = it * 256 + tid;          // uint4 index; row n = o>>4 (16 uint4/row)
        int n = o >> 4, kq8 = o & 15;
        *(uint4*)&Wt[n * 136 + kq8 * 8] = ((const uint4*)Wtb)[o];
    }
    // stage xb[r][k] = bf16(x[r0+r][k]); zero-pad rows >= N
    {
        int row = tid >> 2;          // 0..63
        int q   = tid & 3;           // col quarter
        int grow = r0 + row;
#pragma unroll
        for (int i = 0; i < 8; ++i) {
            float4 v = make_float4(0.f, 0.f, 0.f, 0.f);
            if (grow < N) v = *(const float4*)&x[(size_t)grow * 128 + q * 32 + i * 4];
            ushort4 o;
            o.x = f2bf(v.x); o.y = f2bf(v.y); o.z = f2bf(v.z); o.w = f2bf(v.w);
            *(ushort4*)&xb[row * 136 + q * 32 + i * 4] = o;
        }
    }
    __syncthreads();

    const int wave = tid >> 6;
    const int l    = tid & 63;
    const int c    = l & 15;         // col-in-tile / row-in-A
    const int kq   = l >> 4;         // k-quarter within 32-chunk
    const int wr0  = wave * 16;

    f32x4 acc[8];
#pragma unroll
    for (int n = 0; n < 8; ++n) acc[n] = (f32x4){0.f, 0.f, 0.f, 0.f};

#pragma unroll
    for (int kk = 0; kk < 4; ++kk) {
        int koff = kk * 32 + kq * 8;
        short8 a = *(short8*)&xb[(wr0 + c) * 136 + koff];
#pragma unroll
        for (int n = 0; n < 8; ++n) {
            short8 b = *(short8*)&Wt[(n * 16 + c) * 136 + koff];
            acc[n] = __builtin_amdgcn_mfma_f32_16x16x32_bf16(a, b, acc[n], 0, 0, 0);
        }
    }

    // epilogue: lane holds D[row = wr0 + kq*4 + j][col = 16n + c], j=0..3
    float al_n[8], ar_n[8];
#pragma unroll
    for (int n = 0; n < 8; ++n) {
        al_n[n] = attn_l[n * 16 + c];
        ar_n[n] = attn_r[n * 16 + c];
    }
#pragma unroll
    for (int j = 0; j < 4; ++j) {
        int lrow = wr0 + kq * 4 + j;
        int grow = r0 + lrow;
        float elv[8], erv[8];
#pragma unroll
        for (int n = 0; n < 8; ++n) {
            float d = acc[n][j];
            xb[lrow * 136 + n * 16 + c] = f2bf(d);   // stage bf16 output (wave-private rows)
            elv[n] = d * al_n[n];
            erv[n] = d * ar_n[n];
        }
#pragma unroll
        for (int n = 0; n < 8; ++n) {
            elv[n] += __shfl_xor(elv[n], 1); elv[n] += __shfl_xor(elv[n], 2);
            elv[n] += __shfl_xor(elv[n], 4); elv[n] += __shfl_xor(elv[n], 8);
            erv[n] += __shfl_xor(erv[n], 1); erv[n] += __shfl_xor(erv[n], 2);
            erv[n] += __shfl_xor(erv[n], 4); erv[n] += __shfl_xor(erv[n], 8);
        }
        if (c == 0 && grow < N) {
            *(float4*)&el[grow * 8]     = make_float4(elv[0], elv[1], elv[2], elv[3]);
            *(float4*)&el[grow * 8 + 4] = make_float4(elv[4], elv[5], elv[6], elv[7]);
            *(float4*)&er[grow * 8]     = make_float4(erv[0], erv[1], erv[2], erv[3]);
            *(float4*)&er[grow * 8 + 4] = make_float4(erv[4], erv[5], erv[6], erv[7]);
        }
    }
    // copy staged bf16 rows to global (wave-private slice; in-wave lgkm ordering suffices)
#pragma unroll
    for (int it = 0; it < 4; ++it) {
        int lrow = wr0 + it * 4 + (l >> 4);
        int grow = r0 + lrow;
        int m = c;
        if (grow < N) {
            uint4 v = *(uint4*)&xb[lrow * 136 + m * 8];
            featb4[(size_t)grow * 16 + m] = v;
        }
    }
}

// ---------------- CSR build, pass 1: bucket edges by dst>>BSHIFT ----------------
// Record packed as (local_dst<<23) | src  (src < 2^17, local_dst < 2^9).
__global__ __launch_bounds__(512) void bucket_scatter_kernel(
    const int* __restrict__ src, const int* __restrict__ dst,
    int* __restrict__ bcur, int* __restrict__ pairs,
    int E, int nbucket)
{
    __shared__ int hist[256];
    __shared__ int base[256];
    const int tid = threadIdx.x;
    const int e0  = blockIdx.x * CHUNK;

    if (tid < 256) hist[tid] = 0;
    __syncthreads();

    int d[16], s[16];
#pragma unroll
    for (int j = 0; j < 4; ++j) {
        int i = e0 + j * 2048 + tid * 4;
        if (i + 4 <= E) {
            int4 dv = *(const int4*)&dst[i];
            int4 sv = *(const int4*)&src[i];
            d[j * 4 + 0] = dv.x; d[j * 4 + 1] = dv.y; d[j * 4 + 2] = dv.z; d[j * 4 + 3] = dv.w;
            s[j * 4 + 0] = sv.x; s[j * 4 + 1] = sv.y; s[j * 4 + 2] = sv.z; s[j * 4 + 3] = sv.w;
        } else {
#pragma unroll
            for (int q = 0; q < 4; ++q) {
                d[j * 4 + q] = (i + q < E) ? dst[i + q] : -1;
                s[j * 4 + q] = (i + q < E) ? src[i + q] : 0;
            }
        }
    }
#pragma unroll
    for (int j = 0; j < 16; ++j)
        if (d[j] >= 0) atomicAdd(&hist[d[j] >> BSHIFT], 1);
    __syncthreads();
    if (tid < nbucket) {
        int c = hist[tid];
        base[tid] = c > 0 ? atomicAdd(&bcur[tid], c) : 0;
        hist[tid] = 0;   // reuse as local cursor
    }
    __syncthreads();
#pragma unroll
    for (int j = 0; j < 16; ++j) {
        if (d[j] >= 0) {
            int b = d[j] >> BSHIFT;
            int p = base[b] + atomicAdd(&hist[b], 1);
            if (p < BCAP) pairs[(size_t)b * BCAP + p] = ((d[j] & 511) << 23) | s[j];
        }
    }
}

// ---------------- CSR build, pass 2: per-bucket node sort; starts 4-aligned ----------------
__global__ __launch_bounds__(512) void bucket_build_kernel(
    const int* __restrict__ pairs, const int* __restrict__ bcur,
    int* __restrict__ csr, int* __restrict__ obeg, int* __restrict__ oend,
    int N)
{
    __shared__ int cnt[512];
    __shared__ int scn[512];
    __shared__ int cur[512];
    const int tid = threadIdx.x;
    const int b   = blockIdx.x;
    const int n0  = b << BSHIFT;
    const int cb  = min(bcur[b], BCAP);
    const int* bp = pairs + (size_t)b * BCAP;

    cnt[tid] = 0;
    __syncthreads();
    for (int i = tid; i < cb; i += 512)
        atomicAdd(&cnt[((uint32)bp[i]) >> 23], 1);
    __syncthreads();
    int pc = (cnt[tid] + 3) & ~3;       // pad each node's segment to multiple of 4
    scn[tid] = pc;
    __syncthreads();
    for (int off = 1; off < 512; off <<= 1) {
        int a = (tid >= off) ? scn[tid - off] : 0;
        __syncthreads();
        scn[tid] += a;
        __syncthreads();
    }
    int excl = scn[tid] - pc;
    cur[tid] = excl;
    int g = n0 + tid;
    if (g < N) {
        obeg[g] = b * BCAP + excl;
        oend[g] = b * BCAP + excl + cnt[tid];
    }
    __syncthreads();
    for (int i = tid; i < cb; i += 512) {
        int v = bp[i];
        int p = atomicAdd(&cur[((uint32)v) >> 23], 1);
        if (p < BCAP) csr[(size_t)b * BCAP + p] = v & 0x7FFFFF;
    }
}

// ---------------- Aggregation: one wave per node, 4 edge-slots x 16 channel-lanes ----------------
// lane = es*16 + c8. Main loop: 16 edges/iter via int4 csr loads (beg 4-aligned),
// 8 independent gathers in flight per lane.
__global__ __launch_bounds__(256) void aggregate_kernel(
    const uint4* __restrict__ featb4, const float* __restrict__ el,
    const float* __restrict__ er, const int* __restrict__ obeg,
    const int* __restrict__ oend, const int* __restrict__ csr_src,
    uint4* __restrict__ hpreb4, int N)
{
    int node = blockIdx.x * 4 + (threadIdx.x >> 6);
    if (node >= N) return;
    int lane = threadIdx.x & 63;
    int es   = lane >> 4;
    int c8   = lane & 15;
    int h    = c8 >> 1;
    float er_h = er[node * 8 + h];
    int beg = obeg[node], end = oend[node];
    float a0 = 0.f, a1 = 0.f, a2 = 0.f, a3 = 0.f;
    float a4 = 0.f, a5 = 0.f, a6 = 0.f, a7 = 0.f, ssum = 0.f;
    int e = beg;
    // 16 edges per iteration: slot es owns edges e+4es .. e+4es+3
    for (; e + 16 <= end; e += 16) {
        int4 sv = *(const int4*)&csr_src[e + es * 4];
        float e0 = el[sv.x * 8 + h];
        float e1 = el[sv.y * 8 + h];
        float e2 = el[sv.z * 8 + h];
        float e3 = el[sv.w * 8 + h];
        uint4 f0 = featb4[(size_t)sv.x * 16 + c8];
        uint4 f1 = featb4[(size_t)sv.y * 16 + c8];
        uint4 f2 = featb4[(size_t)sv.z * 16 + c8];
        uint4 f3 = featb4[(size_t)sv.w * 16 + c8];
        float v0 = e0 + er_h; v0 = fmaxf(v0, NEG_SLOPE * v0);
        float v1 = e1 + er_h; v1 = fmaxf(v1, NEG_SLOPE * v1);
        float v2 = e2 + er_h; v2 = fmaxf(v2, NEG_SLOPE * v2);
        float v3 = e3 + er_h; v3 = fmaxf(v3, NEG_SLOPE * v3);
        float x0 = __expf(v0), x1 = __expf(v1), x2 = __expf(v2), x3 = __expf(v3);
        ssum += (x0 + x1) + (x2 + x3);
        a0 = fmaf(x0, bflo(f0.x), a0); a1 = fmaf(x0, bfhi(f0.x), a1);
        a2 = fmaf(x0, bflo(f0.y), a2); a3 = fmaf(x0, bfhi(f0.y), a3);
        a4 = fmaf(x0, bflo(f0.z), a4); a5 = fmaf(x0, bfhi(f0.z), a5);
        a6 = fmaf(x0, bflo(f0.w), a6); a7 = fmaf(x0, bfhi(f0.w), a7);
        a0 = fmaf(x1, bflo(f1.x), a0); a1 = fmaf(x1, bfhi(f1.x), a1);
        a2 = fmaf(x1, bflo(f1.y), a2); a3 = fmaf(x1, bfhi(f1.y), a3);
        a4 = fmaf(x1, bflo(f1.z), a4); a5 = fmaf(x1, bfhi(f1.z), a5);
        a6 = fmaf(x1, bflo(f1.w), a6); a7 = fmaf(x1, bfhi(f1.w), a7);
        a0 = fmaf(x2, bflo(f2.x), a0); a1 = fmaf(x2, bfhi(f2.x), a1);
        a2 = fmaf(x2, bflo(f2.y), a2); a3 = fmaf(x2, bfhi(f2.y), a3);
        a4 = fmaf(x2, bflo(f2.z), a4); a5 = fmaf(x2, bfhi(f2.z), a5);
        a6 = fmaf(x2, bflo(f2.w), a6); a7 = fmaf(x2, bfhi(f2.w), a7);
        a0 = fmaf(x3, bflo(f3.x), a0); a1 = fmaf(x3, bfhi(f3.x), a1);
        a2 = fmaf(x3, bflo(f3.y), a2); a3 = fmaf(x3, bfhi(f3.y), a3);
        a4 = fmaf(x3, bflo(f3.z), a4); a5 = fmaf(x3, bfhi(f3.z), a5);
        a6 = fmaf(x3, bflo(f3.w), a6); a7 = fmaf(x3, bfhi(f3.w), a7);
    }
    for (; e + 4 <= end; e += 4) {
        int sA = csr_src[e + es];
        float eA = el[sA * 8 + h];
        uint4 fA = featb4[(size_t)sA * 16 + c8];
        float evA = eA + er_h; evA = fmaxf(evA, NEG_SLOPE * evA);
        float exA = __expf(evA);
        ssum += exA;
        a0 = fmaf(exA, bflo(fA.x), a0); a1 = fmaf(exA, bfhi(fA.x), a1);
        a2 = fmaf(exA, bflo(fA.y), a2); a3 = fmaf(exA, bfhi(fA.y), a3);
        a4 = fmaf(exA, bflo(fA.z), a4); a5 = fmaf(exA, bfhi(fA.z), a5);
        a6 = fmaf(exA, bflo(fA.w), a6); a7 = fmaf(exA, bfhi(fA.w), a7);
    }
    if (e < end) {   // tail 1..3 edges, mask invalid slots
        int idx = e + es;
        int sc = csr_src[min(idx, end - 1)];
        float ea = el[sc * 8 + h];
        uint4 f = featb4[(size_t)sc * 16 + c8];
        float ev = ea + er_h; ev = fmaxf(ev, NEG_SLOPE * ev);
        float ex = (idx < end) ? __expf(ev) : 0.f;
        ssum += ex;
        a0 = fmaf(ex, bflo(f.x), a0); a1 = fmaf(ex, bfhi(f.x), a1);
        a2 = fmaf(ex, bflo(f.y), a2); a3 = fmaf(ex, bfhi(f.y), a3);
        a4 = fmaf(ex, bflo(f.z), a4); a5 = fmaf(ex, bfhi(f.z), a5);
        a6 = fmaf(ex, bflo(f.w), a6); a7 = fmaf(ex, bfhi(f.w), a7);
    }
    // combine the four edge slots
    ssum += __shfl_xor(ssum, 16); ssum += __shfl_xor(ssum, 32);
    a0 += __shfl_xor(a0, 16); a0 += __shfl_xor(a0, 32);
    a1 += __shfl_xor(a1, 16); a1 += __shfl_xor(a1, 32);
    a2 += __shfl_xor(a2, 16); a2 += __shfl_xor(a2, 32);
    a3 += __shfl_xor(a3, 16); a3 += __shfl_xor(a3, 32);
    a4 += __shfl_xor(a4, 16); a4 += __shfl_xor(a4, 32);
    a5 += __shfl_xor(a5, 16); a5 += __shfl_xor(a5, 32);
    a6 += __shfl_xor(a6, 16); a6 += __shfl_xor(a6, 32);
    a7 += __shfl_xor(a7, 16); a7 += __shfl_xor(a7, 32);
    float inv = ssum > 0.f ? 1.0f / ssum : 0.f;
    if (es == 0) {
        uint4 o;
        o.x = (uint32)f2bf(a0 * inv) | ((uint32)f2bf(a1 * inv) << 16);
        o.y = (uint32)f2bf(a2 * inv) | ((uint32)f2bf(a3 * inv) << 16);
        o.z = (uint32)f2bf(a4 * inv) | ((uint32)f2bf(a5 * inv) << 16);
        o.w = (uint32)f2bf(a6 * inv) | ((uint32)f2bf(a7 * inv) << 16);
        hpreb4[(size_t)node * 16 + c8] = o;
    }
}

// ---------------- BatchNorm stats (bf16 hpre input) ----------------
__global__ __launch_bounds__(256) void stats_kernel(const uint32* __restrict__ hpreb,
                                                    float* __restrict__ gsum,
                                                    float* __restrict__ gsumsq, int N) {
    __shared__ float r1[256], r2[256], r3[256], r4[256];
    int tid = threadIdx.x;
    int cp = tid & 63;          // channel pair: channels 2cp, 2cp+1
    int rg = tid >> 6;          // row group 0..3
    float s1l = 0.f, s2l = 0.f, s1h = 0.f, s2h = 0.f;
    for (int r = blockIdx.x * 4 + rg; r < N; r += gridDim.x * 4) {
        uint32 v = hpreb[(size_t)r * 64 + cp];
        float v0 = bflo(v), v1 = bfhi(v);
        s1l += v0; s2l = fmaf(v0, v0, s2l);
        s1h += v1; s2h = fmaf(v1, v1, s2h);
    }
    r1[tid] = s1l; r2[tid] = s2l; r3[tid] = s1h; r4[tid] = s2h;
    __syncthreads();
    if (tid < 64) {
        float t1 = r1[tid] + r1[tid + 64] + r1[tid + 128] + r1[tid + 192];
        float t2 = r2[tid] + r2[tid + 64] + r2[tid + 128] + r2[tid + 192];
        float t3 = r3[tid] + r3[tid + 64] + r3[tid + 128] + r3[tid + 192];
        float t4 = r4[tid] + r4[tid + 64] + r4[tid + 128] + r4[tid + 192];
        atomicAdd(&gsum[tid * 2], t1);
        atomicAdd(&gsumsq[tid * 2], t2);
        atomicAdd(&gsum[tid * 2 + 1], t3);
        atomicAdd(&gsumsq[tid * 2 + 1], t4);
    }
}

__global__ void bnparams_kernel(const float* __restrict__ gsum, const float* __restrict__ gsumsq,
                                const float* __restrict__ gamma, const float* __restrict__ beta,
                                float* __restrict__ scale, float* __restrict__ shift, int N) {
    int c = threadIdx.x;
    if (c < 128) {
        float mu = gsum[c] / (float)N;
        float var = gsumsq[c] / (float)N - mu * mu;
        float sc = gamma[c] * rsqrtf(var + EPSV);
        scale[c] = sc;
        shift[c] = beta[c] - mu * sc;
    }
}

// ---------------- Final: BN + ELU + residual ----------------
__global__ __launch_bounds__(256) void final_kernel(const uint32* __restrict__ hpreb,
                                                    const float* __restrict__ x,
                                                    const float* __restrict__ scale,
                                                    const float* __restrict__ shift,
                                                    float* __restrict__ out, int total2) {
    int i = blockIdx.x * blockDim.x + threadIdx.x;
    if (i >= total2) return;
    int c0 = (i & 63) * 2;
    uint32 hv = hpreb[i];
    float2 xv = ((const float2*)x)[i];
    float t0 = fmaf(bflo(hv), scale[c0], shift[c0]);
    float t1 = fmaf(bfhi(hv), scale[c0 + 1], shift[c0 + 1]);
    t0 = t0 > 0.f ? t0 : expm1f(t0);
    t1 = t1 > 0.f ? t1 : expm1f(t1);
    ((float2*)out)[i] = make_float2(xv.x + t0, xv.y + t1);
}

extern "C" void kernel_launch(void* const* d_in, const int* in_sizes, int n_in,
                              void* d_out, int out_size, void* d_ws, size_t ws_size,
                              hipStream_t stream) {
    const float* x      = (const float*)d_in[0];
    const int*   src    = (const int*)d_in[1];
    const int*   dst    = (const int*)d_in[2];
    const float* W      = (const float*)d_in[3];
    const float* attn_l = (const float*)d_in[4];
    const float* attn_r = (const float*)d_in[5];
    const float* gamma  = (const float*)d_in[7];
    const float* beta   = (const float*)d_in[8];
    // d_in[6] (bias) cancels exactly in batch-stats BN -> skipped.

    const int N = in_sizes[0] / 128;
    const int E = in_sizes[1];
    const int nbucket = (N + 511) >> BSHIFT;

    char* ws = (char*)d_ws;
    size_t off = 0;
    auto alloc = [&](size_t bytes) -> void* {
        void* p = ws + off;
        off += (bytes + 255) & ~(size_t)255;
        return p;
    };
    uint32* featb  = (uint32*)alloc((size_t)N * 64 * 4);            // 25.6MB bf16x2
    uint32* hpreb  = (uint32*)alloc((size_t)N * 64 * 4);            // 25.6MB bf16x2
    float* el      = (float*)alloc((size_t)N * 8 * 4);
    float* er      = (float*)alloc((size_t)N * 8 * 4);
    int*   pairs   = (int*)alloc((size_t)nbucket * BCAP * 4);       // 8MB packed
    int*   csr     = (int*)alloc((size_t)nbucket * BCAP * 4);       // 8MB
    int*   obeg    = (int*)alloc((size_t)N * 4);
    int*   oend    = (int*)alloc((size_t)N * 4);
    int*   bcur    = (int*)alloc((size_t)nbucket * 4);
    unsigned short* Wtb = (unsigned short*)alloc(128 * 128 * 2);    // 32KB bf16 W^T
    float* gsum    = (float*)alloc(512);
    float* gsumsq  = (float*)alloc(512);
    float* scale   = (float*)alloc(512);
    float* shift   = (float*)alloc(512);

    hipMemsetAsync(bcur, 0, (size_t)nbucket * 4, stream);
    hipMemsetAsync(gsum, 0, 512, stream);
    hipMemsetAsync(gsumsq, 0, 512, stream);

    prep_w_kernel<<<1, 256, 0, stream>>>(W, Wtb);
    gemm_feat_kernel<<<(N + 63) / 64, 256, 0, stream>>>(x, Wtb, attn_l, attn_r,
                                                        (uint4*)featb, el, er, N);
    bucket_scatter_kernel<<<(E + CHUNK - 1) / CHUNK, 512, 0, stream>>>(src, dst, bcur, pairs, E, nbucket);
    bucket_build_kernel<<<nbucket, 512, 0, stream>>>(pairs, bcur, csr, obeg, oend, N);
    aggregate_kernel<<<(N + 3) / 4, 256, 0, stream>>>((const uint4*)featb, el, er, obeg, oend, csr,
                                                      (uint4*)hpreb, N);
    stats_kernel<<<256, 256, 0, stream>>>(hpreb, gsum, gsumsq, N);
    bnparams_kernel<<<1, 128, 0, stream>>>(gsum, gsumsq, gamma, beta, scale, shift, N);
    final_kernel<<<(N * 64 + 255) / 256, 256, 0, stream>>>(hpreb, x, scale, shift, (float*)d_out, N * 64);
}

// Round 8
// 214.362 us; speedup vs baseline: 1.0509x; 1.0509x over previous
//
#include <hip/hip_runtime.h>
#include <math.h>

typedef unsigned int uint32;
typedef __attribute__((ext_vector_type(8))) short short8;   // bf16x8 MFMA frag
typedef __attribute__((ext_vector_type(4))) float f32x4;    // MFMA acc

#define NEG_SLOPE 0.2f
#define EPSV 1e-5f
#define BSHIFT 9                 // 512 nodes per bucket
#define BCAP 10240               // per-bucket edge capacity (avg ~8192)
#define CHUNK 8192               // edges per block in bucket_scatter (512 thr x 16)

__device__ __forceinline__ unsigned short f2bf(float v) {
    unsigned u = __float_as_uint(v);
    unsigned r = (u + 0x7fffu + ((u >> 16) & 1u)) >> 16;   // RNE
    return (unsigned short)r;
}
__device__ __forceinline__ float bflo(uint32 p) { return __uint_as_float(p << 16); }
__device__ __forceinline__ float bfhi(uint32 p) { return __uint_as_float(p & 0xffff0000u); }

// ---------------- Prep: Wtb2 = [144][128] bf16: rows 0-127 = W^T,
// rows 128-135 = WL^T (attn_l folded), rows 136-143 = WR^T (attn_r folded).
__global__ __launch_bounds__(256) void prep_w_kernel(
    const float* __restrict__ W, const float* __restrict__ attn_l,
    const float* __restrict__ attn_r, unsigned short* __restrict__ Wtb2)
{
    const int b = blockIdx.x, tid = threadIdx.x;
    if (b < 8) {
        // transpose-convert rows n = b*16 .. b*16+15
#pragma unroll
        for (int it = 0; it < 8; ++it) {
            int o = b * 2048 + it * 256 + tid;   // o = n*128 + k
            int n = o >> 7, k = o & 127;
            Wtb2[o] = f2bf(W[k * 128 + n]);
        }
    } else {
        // WL/WR: el = x @ WL with WL[k] = sum_d W[k][16h+d]*attn_l[h][d]
#pragma unroll
        for (int i = 0; i < 8; ++i) {
            int o = tid * 8 + i;                 // 0..2047
            int r = o >> 7;                      // 0..15
            int k = o & 127;
            int h = r & 7;
            const float* av = (r < 8) ? attn_l : attn_r;
            float s = 0.f;
#pragma unroll
            for (int d = 0; d < 16; ++d)
                s += W[k * 128 + h * 16 + d] * av[h * 16 + d];
            Wtb2[(128 + r) * 128 + k] = f2bf(s);
        }
    }
}

// ---------------- Kernel A: [feat | el | er] = x @ [W | WL | WR] via MFMA bf16 ----------------
// Block: 256 thr (4 waves), 64 rows x 144 cols, K=128.
__global__ __launch_bounds__(256) void gemm_feat_kernel(
    const float* __restrict__ x, const unsigned short* __restrict__ Wtb2,
    uint4* __restrict__ featb4, float* __restrict__ el, float* __restrict__ er,
    int N)
{
    __shared__ unsigned short Wt[144 * 136];   // 39.2KB
    __shared__ unsigned short xb[64 * 136];    // 17.4KB

    const int tid = threadIdx.x;
    const int r0  = blockIdx.x * 64;

    // stage Wt (2304 uint4, coalesced)
#pragma unroll
    for (int it = 0; it < 9; ++it) {
        int o = it * 256 + tid;          // uint4 index; 16 uint4 per row
        int n = o >> 4, kq8 = o & 15;
        *(uint4*)&Wt[n * 136 + kq8 * 8] = ((const uint4*)Wtb2)[o];
    }
    // stage xb[r][k] = bf16(x[r0+r][k]); zero-pad rows >= N
    {
        int row = tid >> 2;          // 0..63
        int q   = tid & 3;           // col quarter
        int grow = r0 + row;
#pragma unroll
        for (int i = 0; i < 8; ++i) {
            float4 v = make_float4(0.f, 0.f, 0.f, 0.f);
            if (grow < N) v = *(const float4*)&x[(size_t)grow * 128 + q * 32 + i * 4];
            ushort4 o;
            o.x = f2bf(v.x); o.y = f2bf(v.y); o.z = f2bf(v.z); o.w = f2bf(v.w);
            *(ushort4*)&xb[row * 136 + q * 32 + i * 4] = o;
        }
    }
    __syncthreads();

    const int wave = tid >> 6;
    const int l    = tid & 63;
    const int c    = l & 15;         // output col within tile / A row
    const int kq   = l >> 4;         // k-quarter
    const int wr0  = wave * 16;

    f32x4 acc[9];
#pragma unroll
    for (int n = 0; n < 9; ++n) acc[n] = (f32x4){0.f, 0.f, 0.f, 0.f};

#pragma unroll
    for (int kk = 0; kk < 4; ++kk) {
        int koff = kk * 32 + kq * 8;
        short8 a = *(short8*)&xb[(wr0 + c) * 136 + koff];
#pragma unroll
        for (int n = 0; n < 9; ++n) {
            short8 b = *(short8*)&Wt[(n * 16 + c) * 136 + koff];
            acc[n] = __builtin_amdgcn_mfma_f32_16x16x32_bf16(a, b, acc[n], 0, 0, 0);
        }
    }

    // epilogue: lane holds D[row = wr0 + kq*4 + j][col = 16n + c], j=0..3
#pragma unroll
    for (int j = 0; j < 4; ++j) {
        int lrow = wr0 + kq * 4 + j;
        int grow = r0 + lrow;
#pragma unroll
        for (int n = 0; n < 8; ++n)
            xb[lrow * 136 + n * 16 + c] = f2bf(acc[n][j]);   // wave-private rows
        if (grow < N) {
            float d8 = acc[8][j];
            if (c < 8) el[grow * 8 + c] = d8;
            else       er[grow * 8 + (c - 8)] = d8;
        }
    }
    // copy staged bf16 feat rows to global (wave-private slice)
#pragma unroll
    for (int it = 0; it < 4; ++it) {
        int lrow = wr0 + it * 4 + (l >> 4);
        int grow = r0 + lrow;
        if (grow < N) {
            uint4 v = *(uint4*)&xb[lrow * 136 + c * 8];
            featb4[(size_t)grow * 16 + c] = v;
        }
    }
}

// ---------------- CSR build, pass 1: bucket edges by dst>>BSHIFT ----------------
__global__ __launch_bounds__(512) void bucket_scatter_kernel(
    const int* __restrict__ src, const int* __restrict__ dst,
    int* __restrict__ bcur, int* __restrict__ pairs,
    int E, int nbucket)
{
    __shared__ int hist[256];
    __shared__ int base[256];
    const int tid = threadIdx.x;
    const int e0  = blockIdx.x * CHUNK;

    if (tid < 256) hist[tid] = 0;
    __syncthreads();

    int d[16], s[16];
#pragma unroll
    for (int j = 0; j < 4; ++j) {
        int i = e0 + j * 2048 + tid * 4;
        if (i + 4 <= E) {
            int4 dv = *(const int4*)&dst[i];
            int4 sv = *(const int4*)&src[i];
            d[j * 4 + 0] = dv.x; d[j * 4 + 1] = dv.y; d[j * 4 + 2] = dv.z; d[j * 4 + 3] = dv.w;
            s[j * 4 + 0] = sv.x; s[j * 4 + 1] = sv.y; s[j * 4 + 2] = sv.z; s[j * 4 + 3] = sv.w;
        } else {
#pragma unroll
            for (int q = 0; q < 4; ++q) {
                d[j * 4 + q] = (i + q < E) ? dst[i + q] : -1;
                s[j * 4 + q] = (i + q < E) ? src[i + q] : 0;
            }
        }
    }
#pragma unroll
    for (int j = 0; j < 16; ++j)
        if (d[j] >= 0) atomicAdd(&hist[d[j] >> BSHIFT], 1);
    __syncthreads();
    if (tid < nbucket) {
        int c = hist[tid];
        base[tid] = c > 0 ? atomicAdd(&bcur[tid], c) : 0;
        hist[tid] = 0;   // reuse as local cursor
    }
    __syncthreads();
#pragma unroll
    for (int j = 0; j < 16; ++j) {
        if (d[j] >= 0) {
            int b = d[j] >> BSHIFT;
            int p = base[b] + atomicAdd(&hist[b], 1);
            if (p < BCAP) pairs[(size_t)b * BCAP + p] = ((d[j] & 511) << 23) | s[j];
        }
    }
}

// ---------------- CSR build, pass 2: per-bucket node sort; starts 4-aligned ----------------
__global__ __launch_bounds__(512) void bucket_build_kernel(
    const int* __restrict__ pairs, const int* __restrict__ bcur,
    int* __restrict__ csr, int* __restrict__ obeg, int* __restrict__ oend,
    int N)
{
    __shared__ int cnt[512];
    __shared__ int scn[512];
    __shared__ int cur[512];
    const int tid = threadIdx.x;
    const int b   = blockIdx.x;
    const int n0  = b << BSHIFT;
    const int cb  = min(bcur[b], BCAP);
    const int* bp = pairs + (size_t)b * BCAP;

    cnt[tid] = 0;
    __syncthreads();
    for (int i = tid; i < cb; i += 512)
        atomicAdd(&cnt[((uint32)bp[i]) >> 23], 1);
    __syncthreads();
    int pc = (cnt[tid] + 3) & ~3;       // pad each node's segment to multiple of 4
    scn[tid] = pc;
    __syncthreads();
    for (int off = 1; off < 512; off <<= 1) {
        int a = (tid >= off) ? scn[tid - off] : 0;
        __syncthreads();
        scn[tid] += a;
        __syncthreads();
    }
    int excl = scn[tid] - pc;
    cur[tid] = excl;
    int g = n0 + tid;
    if (g < N) {
        obeg[g] = b * BCAP + excl;
        oend[g] = b * BCAP + excl + cnt[tid];
    }
    __syncthreads();
    for (int i = tid; i < cb; i += 512) {
        int v = bp[i];
        int p = atomicAdd(&cur[((uint32)v) >> 23], 1);
        if (p < BCAP) csr[(size_t)b * BCAP + p] = v & 0x7FFFFF;
    }
}

// ---------------- Aggregation: one wave per node, 4 edge-slots x 16 channel-lanes ----------------
__global__ __launch_bounds__(256) void aggregate_kernel(
    const uint4* __restrict__ featb4, const float* __restrict__ el,
    const float* __restrict__ er, const int* __restrict__ obeg,
    const int* __restrict__ oend, const int* __restrict__ csr_src,
    uint4* __restrict__ hpreb4, int N)
{
    int node = blockIdx.x * 4 + (threadIdx.x >> 6);
    if (node >= N) return;
    int lane = threadIdx.x & 63;
    int es   = lane >> 4;
    int c8   = lane & 15;
    int h    = c8 >> 1;
    float er_h = er[node * 8 + h];
    int beg = obeg[node], end = oend[node];
    float a0 = 0.f, a1 = 0.f, a2 = 0.f, a3 = 0.f;
    float a4 = 0.f, a5 = 0.f, a6 = 0.f, a7 = 0.f, ssum = 0.f;
    int e = beg;
    // 16 edges per iteration: slot es owns edges e+4es .. e+4es+3
    for (; e + 16 <= end; e += 16) {
        int4 sv = *(const int4*)&csr_src[e + es * 4];
        float e0 = el[sv.x * 8 + h];
        float e1 = el[sv.y * 8 + h];
        float e2 = el[sv.z * 8 + h];
        float e3 = el[sv.w * 8 + h];
        uint4 f0 = featb4[(size_t)sv.x * 16 + c8];
        uint4 f1 = featb4[(size_t)sv.y * 16 + c8];
        uint4 f2 = featb4[(size_t)sv.z * 16 + c8];
        uint4 f3 = featb4[(size_t)sv.w * 16 + c8];
        float v0 = e0 + er_h; v0 = fmaxf(v0, NEG_SLOPE * v0);
        float v1 = e1 + er_h; v1 = fmaxf(v1, NEG_SLOPE * v1);
        float v2 = e2 + er_h; v2 = fmaxf(v2, NEG_SLOPE * v2);
        float v3 = e3 + er_h; v3 = fmaxf(v3, NEG_SLOPE * v3);
        float x0 = __expf(v0), x1 = __expf(v1), x2 = __expf(v2), x3 = __expf(v3);
        ssum += (x0 + x1) + (x2 + x3);
        a0 = fmaf(x0, bflo(f0.x), a0); a1 = fmaf(x0, bfhi(f0.x), a1);
        a2 = fmaf(x0, bflo(f0.y), a2); a3 = fmaf(x0, bfhi(f0.y), a3);
        a4 = fmaf(x0, bflo(f0.z), a4); a5 = fmaf(x0, bfhi(f0.z), a5);
        a6 = fmaf(x0, bflo(f0.w), a6); a7 = fmaf(x0, bfhi(f0.w), a7);
        a0 = fmaf(x1, bflo(f1.x), a0); a1 = fmaf(x1, bfhi(f1.x), a1);
        a2 = fmaf(x1, bflo(f1.y), a2); a3 = fmaf(x1, bfhi(f1.y), a3);
        a4 = fmaf(x1, bflo(f1.z), a4); a5 = fmaf(x1, bfhi(f1.z), a5);
        a6 = fmaf(x1, bflo(f1.w), a6); a7 = fmaf(x1, bfhi(f1.w), a7);
        a0 = fmaf(x2, bflo(f2.x), a0); a1 = fmaf(x2, bfhi(f2.x), a1);
        a2 = fmaf(x2, bflo(f2.y), a2); a3 = fmaf(x2, bfhi(f2.y), a3);
        a4 = fmaf(x2, bflo(f2.z), a4); a5 = fmaf(x2, bfhi(f2.z), a5);
        a6 = fmaf(x2, bflo(f2.w), a6); a7 = fmaf(x2, bfhi(f2.w), a7);
        a0 = fmaf(x3, bflo(f3.x), a0); a1 = fmaf(x3, bfhi(f3.x), a1);
        a2 = fmaf(x3, bflo(f3.y), a2); a3 = fmaf(x3, bfhi(f3.y), a3);
        a4 = fmaf(x3, bflo(f3.z), a4); a5 = fmaf(x3, bfhi(f3.z), a5);
        a6 = fmaf(x3, bflo(f3.w), a6); a7 = fmaf(x3, bfhi(f3.w), a7);
    }
    for (; e + 4 <= end; e += 4) {
        int sA = csr_src[e + es];
        float eA = el[sA * 8 + h];
        uint4 fA = featb4[(size_t)sA * 16 + c8];
        float evA = eA + er_h; evA = fmaxf(evA, NEG_SLOPE * evA);
        float exA = __expf(evA);
        ssum += exA;
        a0 = fmaf(exA, bflo(fA.x), a0); a1 = fmaf(exA, bfhi(fA.x), a1);
        a2 = fmaf(exA, bflo(fA.y), a2); a3 = fmaf(exA, bfhi(fA.y), a3);
        a4 = fmaf(exA, bflo(fA.z), a4); a5 = fmaf(exA, bfhi(fA.z), a5);
        a6 = fmaf(exA, bflo(fA.w), a6); a7 = fmaf(exA, bfhi(fA.w), a7);
    }
    if (e < end) {   // tail 1..3 edges, mask invalid slots
        int idx = e + es;
        int sc = csr_src[min(idx, end - 1)];
        float ea = el[sc * 8 + h];
        uint4 f = featb4[(size_t)sc * 16 + c8];
        float ev = ea + er_h; ev = fmaxf(ev, NEG_SLOPE * ev);
        float ex = (idx < end) ? __expf(ev) : 0.f;
        ssum += ex;
        a0 = fmaf(ex, bflo(f.x), a0); a1 = fmaf(ex, bfhi(f.x), a1);
        a2 = fmaf(ex, bflo(f.y), a2); a3 = fmaf(ex, bfhi(f.y), a3);
        a4 = fmaf(ex, bflo(f.z), a4); a5 = fmaf(ex, bfhi(f.z), a5);
        a6 = fmaf(ex, bflo(f.w), a6); a7 = fmaf(ex, bfhi(f.w), a7);
    }
    // combine the four edge slots
    ssum += __shfl_xor(ssum, 16); ssum += __shfl_xor(ssum, 32);
    a0 += __shfl_xor(a0, 16); a0 += __shfl_xor(a0, 32);
    a1 += __shfl_xor(a1, 16); a1 += __shfl_xor(a1, 32);
    a2 += __shfl_xor(a2, 16); a2 += __shfl_xor(a2, 32);
    a3 += __shfl_xor(a3, 16); a3 += __shfl_xor(a3, 32);
    a4 += __shfl_xor(a4, 16); a4 += __shfl_xor(a4, 32);
    a5 += __shfl_xor(a5, 16); a5 += __shfl_xor(a5, 32);
    a6 += __shfl_xor(a6, 16); a6 += __shfl_xor(a6, 32);
    a7 += __shfl_xor(a7, 16); a7 += __shfl_xor(a7, 32);
    float inv = ssum > 0.f ? 1.0f / ssum : 0.f;
    if (es == 0) {
        uint4 o;
        o.x = (uint32)f2bf(a0 * inv) | ((uint32)f2bf(a1 * inv) << 16);
        o.y = (uint32)f2bf(a2 * inv) | ((uint32)f2bf(a3 * inv) << 16);
        o.z = (uint32)f2bf(a4 * inv) | ((uint32)f2bf(a5 * inv) << 16);
        o.w = (uint32)f2bf(a6 * inv) | ((uint32)f2bf(a7 * inv) << 16);
        hpreb4[(size_t)node * 16 + c8] = o;
    }
}

// ---------------- BatchNorm stats (bf16 hpre input) + fused bnparams (last block) ----------------
__global__ __launch_bounds__(256) void stats_kernel(const uint32* __restrict__ hpreb,
                                                    float* __restrict__ gsum,
                                                    float* __restrict__ gsumsq,
                                                    int* __restrict__ ctr,
                                                    const float* __restrict__ gamma,
                                                    const float* __restrict__ beta,
                                                    float* __restrict__ scale,
                                                    float* __restrict__ shift, int N) {
    __shared__ float r1[256], r2[256], r3[256], r4[256];
    __shared__ int lastdone;
    int tid = threadIdx.x;
    int cp = tid & 63;          // channel pair: channels 2cp, 2cp+1
    int rg = tid >> 6;          // row group 0..3
    float s1l = 0.f, s2l = 0.f, s1h = 0.f, s2h = 0.f;
    for (int r = blockIdx.x * 4 + rg; r < N; r += gridDim.x * 4) {
        uint32 v = hpreb[(size_t)r * 64 + cp];
        float v0 = bflo(v), v1 = bfhi(v);
        s1l += v0; s2l = fmaf(v0, v0, s2l);
        s1h += v1; s2h = fmaf(v1, v1, s2h);
    }
    r1[tid] = s1l; r2[tid] = s2l; r3[tid] = s1h; r4[tid] = s2h;
    __syncthreads();
    if (tid < 64) {
        float t1 = r1[tid] + r1[tid + 64] + r1[tid + 128] + r1[tid + 192];
        float t2 = r2[tid] + r2[tid + 64] + r2[tid + 128] + r2[tid + 192];
        float t3 = r3[tid] + r3[tid + 64] + r3[tid + 128] + r3[tid + 192];
        float t4 = r4[tid] + r4[tid + 64] + r4[tid + 128] + r4[tid + 192];
        atomicAdd(&gsum[tid * 2], t1);
        atomicAdd(&gsumsq[tid * 2], t2);
        atomicAdd(&gsum[tid * 2 + 1], t3);
        atomicAdd(&gsumsq[tid * 2 + 1], t4);
    }
    __threadfence();
    __syncthreads();
    if (tid == 0) lastdone = (atomicAdd(ctr, 1) == (int)gridDim.x - 1);
    __syncthreads();
    if (lastdone && tid < 128) {
        float sv  = atomicAdd(&gsum[tid], 0.f);     // device-scope read
        float sq  = atomicAdd(&gsumsq[tid], 0.f);
        float mu  = sv / (float)N;
        float var = sq / (float)N - mu * mu;
        float sc  = gamma[tid] * rsqrtf(var + EPSV);
        scale[tid] = sc;
        shift[tid] = beta[tid] - mu * sc;
    }
}

// ---------------- Final: BN + ELU + residual ----------------
__global__ __launch_bounds__(256) void final_kernel(const uint32* __restrict__ hpreb,
                                                    const float* __restrict__ x,
                                                    const float* __restrict__ scale,
                                                    const float* __restrict__ shift,
                                                    float* __restrict__ out, int total2) {
    int i = blockIdx.x * blockDim.x + threadIdx.x;
    if (i >= total2) return;
    int c0 = (i & 63) * 2;
    uint32 hv = hpreb[i];
    float2 xv = ((const float2*)x)[i];
    float t0 = fmaf(bflo(hv), scale[c0], shift[c0]);
    float t1 = fmaf(bfhi(hv), scale[c0 + 1], shift[c0 + 1]);
    t0 = t0 > 0.f ? t0 : expm1f(t0);
    t1 = t1 > 0.f ? t1 : expm1f(t1);
    ((float2*)out)[i] = make_float2(xv.x + t0, xv.y + t1);
}

extern "C" void kernel_launch(void* const* d_in, const int* in_sizes, int n_in,
                              void* d_out, int out_size, void* d_ws, size_t ws_size,
                              hipStream_t stream) {
    const float* x      = (const float*)d_in[0];
    const int*   src    = (const int*)d_in[1];
    const int*   dst    = (const int*)d_in[2];
    const float* W      = (const float*)d_in[3];
    const float* attn_l = (const float*)d_in[4];
    const float* attn_r = (const float*)d_in[5];
    const float* gamma  = (const float*)d_in[7];
    const float* beta   = (const float*)d_in[8];
    // d_in[6] (bias) cancels exactly in batch-stats BN -> skipped.

    const int N = in_sizes[0] / 128;
    const int E = in_sizes[1];
    const int nbucket = (N + 511) >> BSHIFT;

    char* ws = (char*)d_ws;
    size_t off = 0;
    auto alloc = [&](size_t bytes) -> void* {
        void* p = ws + off;
        off += (bytes + 255) & ~(size_t)255;
        return p;
    };
    uint32* featb  = (uint32*)alloc((size_t)N * 64 * 4);            // 25.6MB bf16x2
    uint32* hpreb  = (uint32*)alloc((size_t)N * 64 * 4);            // 25.6MB bf16x2
    float* el      = (float*)alloc((size_t)N * 8 * 4);
    float* er      = (float*)alloc((size_t)N * 8 * 4);
    int*   pairs   = (int*)alloc((size_t)nbucket * BCAP * 4);       // 8MB packed
    int*   csr     = (int*)alloc((size_t)nbucket * BCAP * 4);       // 8MB
    int*   obeg    = (int*)alloc((size_t)N * 4);
    int*   oend    = (int*)alloc((size_t)N * 4);
    int*   bcur    = (int*)alloc((size_t)nbucket * 4);
    unsigned short* Wtb2 = (unsigned short*)alloc(144 * 128 * 2);   // bf16 [W|WL|WR]^T
    float* gsum    = (float*)alloc(512);
    float* gsumsq  = (float*)alloc(512);
    int*   ctr     = (int*)alloc(256);
    float* scale   = (float*)alloc(512);
    float* shift   = (float*)alloc(512);

    hipMemsetAsync(bcur, 0, (size_t)nbucket * 4, stream);
    hipMemsetAsync(gsum, 0, 512 + 512 + 256, stream);   // gsum+gsumsq+ctr contiguous

    prep_w_kernel<<<9, 256, 0, stream>>>(W, attn_l, attn_r, Wtb2);
    gemm_feat_kernel<<<(N + 63) / 64, 256, 0, stream>>>(x, Wtb2, (uint4*)featb, el, er, N);
    bucket_scatter_kernel<<<(E + CHUNK - 1) / CHUNK, 512, 0, stream>>>(src, dst, bcur, pairs, E, nbucket);
    bucket_build_kernel<<<nbucket, 512, 0, stream>>>(pairs, bcur, csr, obeg, oend, N);
    aggregate_kernel<<<(N + 3) / 4, 256, 0, stream>>>((const uint4*)featb, el, er, obeg, oend, csr,
                                                      (uint4*)hpreb, N);
    stats_kernel<<<256, 256, 0, stream>>>(hpreb, gsum, gsumsq, ctr, gamma, beta, scale, shift, N);
    final_kernel<<<(N * 64 + 255) / 256, 256, 0, stream>>>(hpreb, x, scale, shift, (float*)d_out, N * 64);
}

// Round 9
// 194.602 us; speedup vs baseline: 1.1576x; 1.1015x over previous
//
#include <hip/hip_runtime.h>
#include <math.h>

typedef unsigned int uint32;
typedef __attribute__((ext_vector_type(8))) short short8;   // bf16x8 MFMA frag
typedef __attribute__((ext_vector_type(4))) float f32x4;    // MFMA acc

#define NEG_SLOPE 0.2f
#define EPSV 1e-5f
#define BSHIFT 9                 // 512 nodes per bucket
#define BCAP 10240               // per-bucket edge capacity (avg ~8192)
#define SCHUNK 2048              // edges per scatter block (256 thr x 8)

__device__ __forceinline__ unsigned short f2bf(float v) {
    unsigned u = __float_as_uint(v);
    unsigned r = (u + 0x7fffu + ((u >> 16) & 1u)) >> 16;   // RNE
    return (unsigned short)r;
}
__device__ __forceinline__ uint32 pack2(float a, float b) {
    return (uint32)f2bf(a) | ((uint32)f2bf(b) << 16);
}
__device__ __forceinline__ float bflo(uint32 p) { return __uint_as_float(p << 16); }
__device__ __forceinline__ float bfhi(uint32 p) { return __uint_as_float(p & 0xffff0000u); }

// ---------------- Prep: Wtb2 = [144][128] bf16 ([W|WL|WR]^T) + zero-init scratch ----------------
__global__ __launch_bounds__(256) void prep_w_kernel(
    const float* __restrict__ W, const float* __restrict__ attn_l,
    const float* __restrict__ attn_r, unsigned short* __restrict__ Wtb2,
    int* __restrict__ bcur, float* __restrict__ gsum, float* __restrict__ gsumsq,
    int* __restrict__ ctr, int nbucket)
{
    const int b = blockIdx.x, tid = threadIdx.x;
    if (b < 8) {
        // transpose-convert rows n = b*16 .. b*16+15
#pragma unroll
        for (int it = 0; it < 8; ++it) {
            int o = b * 2048 + it * 256 + tid;   // o = n*128 + k
            int n = o >> 7, k = o & 127;
            Wtb2[o] = f2bf(W[k * 128 + n]);
        }
    } else if (b == 8) {
        // WL/WR: el = x @ WL with WL[k] = sum_d W[k][16h+d]*attn_l[h][d]
#pragma unroll
        for (int i = 0; i < 8; ++i) {
            int o = tid * 8 + i;                 // 0..2047
            int r = o >> 7;                      // 0..15
            int k = o & 127;
            int h = r & 7;
            const float* av = (r < 8) ? attn_l : attn_r;
            float s = 0.f;
#pragma unroll
            for (int d = 0; d < 16; ++d)
                s += W[k * 128 + h * 16 + d] * av[h * 16 + d];
            Wtb2[(128 + r) * 128 + k] = f2bf(s);
        }
    } else {
        if (tid < nbucket) bcur[tid] = 0;
        if (tid < 128) { gsum[tid] = 0.f; gsumsq[tid] = 0.f; }
        if (tid == 0) *ctr = 0;
    }
}

// ---------------- Fat kernel: gemm blocks [0,NG) + bucket_scatter blocks [NG,NG+NS) ----------------
// gemm: 64 rows x 144 cols, K=128, A-frags direct from global, LDS = Wt only (39KB).
__global__ __launch_bounds__(256) void fat_kernel(
    const float* __restrict__ x, const unsigned short* __restrict__ Wtb2,
    uint4* __restrict__ featb4, float* __restrict__ el, float* __restrict__ er,
    const int* __restrict__ src, const int* __restrict__ dst,
    int* __restrict__ bcur, int* __restrict__ pairs,
    int N, int E, int nbucket, int NG)
{
    __shared__ __align__(16) unsigned short sh[144 * 136];   // 39168B
    const int tid = threadIdx.x;

    if ((int)blockIdx.x < NG) {
        // ---------------- GEMM branch ----------------
        const int r0 = blockIdx.x * 64;
        // stage Wt (2304 uint4, coalesced)
#pragma unroll
        for (int it = 0; it < 9; ++it) {
            int o = it * 256 + tid;          // uint4 index; 16 uint4 per row
            int n = o >> 4, kq8 = o & 15;
            *(uint4*)&sh[n * 136 + kq8 * 8] = ((const uint4*)Wtb2)[o];
        }
        __syncthreads();

        const int wave = tid >> 6;
        const int l    = tid & 63;
        const int c    = l & 15;
        const int kq   = l >> 4;
        const int wr0  = wave * 16;
        const int row  = r0 + wr0 + c;
        const float* xr = x + (size_t)row * 128;
        const bool rok = (row < N);

        f32x4 acc[9];
#pragma unroll
        for (int n = 0; n < 9; ++n) acc[n] = (f32x4){0.f, 0.f, 0.f, 0.f};

#pragma unroll
        for (int kk = 0; kk < 4; ++kk) {
            int koff = kk * 32 + kq * 8;
            union { short8 v; uint32 u[4]; } A;
            if (rok) {
                float4 v0 = *(const float4*)(xr + koff);
                float4 v1 = *(const float4*)(xr + koff + 4);
                A.u[0] = pack2(v0.x, v0.y); A.u[1] = pack2(v0.z, v0.w);
                A.u[2] = pack2(v1.x, v1.y); A.u[3] = pack2(v1.z, v1.w);
            } else {
                A.u[0] = A.u[1] = A.u[2] = A.u[3] = 0u;
            }
#pragma unroll
            for (int n = 0; n < 9; ++n) {
                short8 b = *(short8*)&sh[(n * 16 + c) * 136 + koff];
                acc[n] = __builtin_amdgcn_mfma_f32_16x16x32_bf16(A.v, b, acc[n], 0, 0, 0);
            }
        }

        __syncthreads();   // all waves done reading Wt; reuse sh as output stage
        // lane holds D[row = wr0 + kq*4 + j][col = 16n + c], j=0..3
#pragma unroll
        for (int j = 0; j < 4; ++j) {
            int lrow = wr0 + kq * 4 + j;
            int grow = r0 + lrow;
#pragma unroll
            for (int n = 0; n < 8; ++n)
                sh[lrow * 136 + n * 16 + c] = f2bf(acc[n][j]);   // wave-private rows
            if (grow < N) {
                float d8 = acc[8][j];
                if (c < 8) el[grow * 8 + c] = d8;
                else       er[grow * 8 + (c - 8)] = d8;
            }
        }
#pragma unroll
        for (int it = 0; it < 4; ++it) {
            int lrow = wr0 + it * 4 + kq;
            int grow = r0 + lrow;
            if (grow < N) {
                uint4 v = *(uint4*)&sh[lrow * 136 + c * 8];
                featb4[(size_t)grow * 16 + c] = v;
            }
        }
    } else {
        // ---------------- bucket_scatter branch ----------------
        int* hist = (int*)sh;          // 256 ints
        int* base = hist + 256;
        const int e0 = (blockIdx.x - NG) * SCHUNK;

        hist[tid] = 0;
        __syncthreads();

        int d[8], s[8];
#pragma unroll
        for (int j = 0; j < 2; ++j) {
            int i = e0 + j * 1024 + tid * 4;
            if (i + 4 <= E) {
                int4 dv = *(const int4*)&dst[i];
                int4 sv = *(const int4*)&src[i];
                d[j * 4 + 0] = dv.x; d[j * 4 + 1] = dv.y; d[j * 4 + 2] = dv.z; d[j * 4 + 3] = dv.w;
                s[j * 4 + 0] = sv.x; s[j * 4 + 1] = sv.y; s[j * 4 + 2] = sv.z; s[j * 4 + 3] = sv.w;
            } else {
#pragma unroll
                for (int q = 0; q < 4; ++q) {
                    d[j * 4 + q] = (i + q < E) ? dst[i + q] : -1;
                    s[j * 4 + q] = (i + q < E) ? src[i + q] : 0;
                }
            }
        }
#pragma unroll
        for (int j = 0; j < 8; ++j)
            if (d[j] >= 0) atomicAdd(&hist[d[j] >> BSHIFT], 1);
        __syncthreads();
        if (tid < nbucket) {
            int c = hist[tid];
            base[tid] = c > 0 ? atomicAdd(&bcur[tid], c) : 0;
            hist[tid] = 0;   // reuse as local cursor
        }
        __syncthreads();
#pragma unroll
        for (int j = 0; j < 8; ++j) {
            if (d[j] >= 0) {
                int b = d[j] >> BSHIFT;
                int p = base[b] + atomicAdd(&hist[b], 1);
                if (p < BCAP) pairs[(size_t)b * BCAP + p] = ((d[j] & 511) << 23) | s[j];
            }
        }
    }
}

// ---------------- CSR build, pass 2: per-bucket node sort; starts 4-aligned ----------------
__global__ __launch_bounds__(1024) void bucket_build_kernel(
    const int* __restrict__ pairs, const int* __restrict__ bcur,
    int* __restrict__ csr, int* __restrict__ obeg, int* __restrict__ oend,
    int N)
{
    __shared__ int cnt[512];
    __shared__ int scn[512];
    __shared__ int cur[512];
    const int tid = threadIdx.x;
    const int b   = blockIdx.x;
    const int n0  = b << BSHIFT;
    const int cb  = min(bcur[b], BCAP);
    const int* bp = pairs + (size_t)b * BCAP;

    if (tid < 512) cnt[tid] = 0;
    __syncthreads();
    for (int i = tid; i < cb; i += 1024)
        atomicAdd(&cnt[((uint32)bp[i]) >> 23], 1);
    __syncthreads();
    int pc = 0;
    if (tid < 512) {
        pc = (cnt[tid] + 3) & ~3;       // pad each node's segment to multiple of 4
        scn[tid] = pc;
    }
    __syncthreads();
    for (int off = 1; off < 512; off <<= 1) {
        int a = (tid >= off && tid < 512) ? scn[tid - off] : 0;
        __syncthreads();
        if (tid < 512) scn[tid] += a;
        __syncthreads();
    }
    if (tid < 512) {
        int excl = scn[tid] - pc;
        cur[tid] = excl;
        int g = n0 + tid;
        if (g < N) {
            obeg[g] = b * BCAP + excl;
            oend[g] = b * BCAP + excl + cnt[tid];
        }
    }
    __syncthreads();
    for (int i = tid; i < cb; i += 1024) {
        int v = bp[i];
        int p = atomicAdd(&cur[((uint32)v) >> 23], 1);
        if (p < BCAP) csr[(size_t)b * BCAP + p] = v & 0x7FFFFF;
    }
}

// ---------------- Aggregation: one wave per node, 4 edge-slots x 16 channel-lanes ----------------
__global__ __launch_bounds__(256) void aggregate_kernel(
    const uint4* __restrict__ featb4, const float* __restrict__ el,
    const float* __restrict__ er, const int* __restrict__ obeg,
    const int* __restrict__ oend, const int* __restrict__ csr_src,
    uint4* __restrict__ hpreb4, int N)
{
    int node = blockIdx.x * 4 + (threadIdx.x >> 6);
    if (node >= N) return;
    int lane = threadIdx.x & 63;
    int es   = lane >> 4;
    int c8   = lane & 15;
    int h    = c8 >> 1;
    float er_h = er[node * 8 + h];
    int beg = obeg[node], end = oend[node];
    float a0 = 0.f, a1 = 0.f, a2 = 0.f, a3 = 0.f;
    float a4 = 0.f, a5 = 0.f, a6 = 0.f, a7 = 0.f, ssum = 0.f;
    int e = beg;
    for (; e + 16 <= end; e += 16) {
        int4 sv = *(const int4*)&csr_src[e + es * 4];
        float e0 = el[sv.x * 8 + h];
        float e1 = el[sv.y * 8 + h];
        float e2 = el[sv.z * 8 + h];
        float e3 = el[sv.w * 8 + h];
        uint4 f0 = featb4[(size_t)sv.x * 16 + c8];
        uint4 f1 = featb4[(size_t)sv.y * 16 + c8];
        uint4 f2 = featb4[(size_t)sv.z * 16 + c8];
        uint4 f3 = featb4[(size_t)sv.w * 16 + c8];
        float v0 = e0 + er_h; v0 = fmaxf(v0, NEG_SLOPE * v0);
        float v1 = e1 + er_h; v1 = fmaxf(v1, NEG_SLOPE * v1);
        float v2 = e2 + er_h; v2 = fmaxf(v2, NEG_SLOPE * v2);
        float v3 = e3 + er_h; v3 = fmaxf(v3, NEG_SLOPE * v3);
        float x0 = __expf(v0), x1 = __expf(v1), x2 = __expf(v2), x3 = __expf(v3);
        ssum += (x0 + x1) + (x2 + x3);
        a0 = fmaf(x0, bflo(f0.x), a0); a1 = fmaf(x0, bfhi(f0.x), a1);
        a2 = fmaf(x0, bflo(f0.y), a2); a3 = fmaf(x0, bfhi(f0.y), a3);
        a4 = fmaf(x0, bflo(f0.z), a4); a5 = fmaf(x0, bfhi(f0.z), a5);
        a6 = fmaf(x0, bflo(f0.w), a6); a7 = fmaf(x0, bfhi(f0.w), a7);
        a0 = fmaf(x1, bflo(f1.x), a0); a1 = fmaf(x1, bfhi(f1.x), a1);
        a2 = fmaf(x1, bflo(f1.y), a2); a3 = fmaf(x1, bfhi(f1.y), a3);
        a4 = fmaf(x1, bflo(f1.z), a4); a5 = fmaf(x1, bfhi(f1.z), a5);
        a6 = fmaf(x1, bflo(f1.w), a6); a7 = fmaf(x1, bfhi(f1.w), a7);
        a0 = fmaf(x2, bflo(f2.x), a0); a1 = fmaf(x2, bfhi(f2.x), a1);
        a2 = fmaf(x2, bflo(f2.y), a2); a3 = fmaf(x2, bfhi(f2.y), a3);
        a4 = fmaf(x2, bflo(f2.z), a4); a5 = fmaf(x2, bfhi(f2.z), a5);
        a6 = fmaf(x2, bflo(f2.w), a6); a7 = fmaf(x2, bfhi(f2.w), a7);
        a0 = fmaf(x3, bflo(f3.x), a0); a1 = fmaf(x3, bfhi(f3.x), a1);
        a2 = fmaf(x3, bflo(f3.y), a2); a3 = fmaf(x3, bfhi(f3.y), a3);
        a4 = fmaf(x3, bflo(f3.z), a4); a5 = fmaf(x3, bfhi(f3.z), a5);
        a6 = fmaf(x3, bflo(f3.w), a6); a7 = fmaf(x3, bfhi(f3.w), a7);
    }
    for (; e + 4 <= end; e += 4) {
        int sA = csr_src[e + es];
        float eA = el[sA * 8 + h];
        uint4 fA = featb4[(size_t)sA * 16 + c8];
        float evA = eA + er_h; evA = fmaxf(evA, NEG_SLOPE * evA);
        float exA = __expf(evA);
        ssum += exA;
        a0 = fmaf(exA, bflo(fA.x), a0); a1 = fmaf(exA, bfhi(fA.x), a1);
        a2 = fmaf(exA, bflo(fA.y), a2); a3 = fmaf(exA, bfhi(fA.y), a3);
        a4 = fmaf(exA, bflo(fA.z), a4); a5 = fmaf(exA, bfhi(fA.z), a5);
        a6 = fmaf(exA, bflo(fA.w), a6); a7 = fmaf(exA, bfhi(fA.w), a7);
    }
    if (e < end) {   // tail 1..3 edges, mask invalid slots
        int idx = e + es;
        int sc = csr_src[min(idx, end - 1)];
        float ea = el[sc * 8 + h];
        uint4 f = featb4[(size_t)sc * 16 + c8];
        float ev = ea + er_h; ev = fmaxf(ev, NEG_SLOPE * ev);
        float ex = (idx < end) ? __expf(ev) : 0.f;
        ssum += ex;
        a0 = fmaf(ex, bflo(f.x), a0); a1 = fmaf(ex, bfhi(f.x), a1);
        a2 = fmaf(ex, bflo(f.y), a2); a3 = fmaf(ex, bfhi(f.y), a3);
        a4 = fmaf(ex, bflo(f.z), a4); a5 = fmaf(ex, bfhi(f.z), a5);
        a6 = fmaf(ex, bflo(f.w), a6); a7 = fmaf(ex, bfhi(f.w), a7);
    }
    ssum += __shfl_xor(ssum, 16); ssum += __shfl_xor(ssum, 32);
    a0 += __shfl_xor(a0, 16); a0 += __shfl_xor(a0, 32);
    a1 += __shfl_xor(a1, 16); a1 += __shfl_xor(a1, 32);
    a2 += __shfl_xor(a2, 16); a2 += __shfl_xor(a2, 32);
    a3 += __shfl_xor(a3, 16); a3 += __shfl_xor(a3, 32);
    a4 += __shfl_xor(a4, 16); a4 += __shfl_xor(a4, 32);
    a5 += __shfl_xor(a5, 16); a5 += __shfl_xor(a5, 32);
    a6 += __shfl_xor(a6, 16); a6 += __shfl_xor(a6, 32);
    a7 += __shfl_xor(a7, 16); a7 += __shfl_xor(a7, 32);
    float inv = ssum > 0.f ? 1.0f / ssum : 0.f;
    if (es == 0) {
        uint4 o;
        o.x = pack2(a0 * inv, a1 * inv);
        o.y = pack2(a2 * inv, a3 * inv);
        o.z = pack2(a4 * inv, a5 * inv);
        o.w = pack2(a6 * inv, a7 * inv);
        hpreb4[(size_t)node * 16 + c8] = o;
    }
}

// ---------------- BatchNorm stats (bf16 hpre input) + fused bnparams (last block) ----------------
__global__ __launch_bounds__(256) void stats_kernel(const uint32* __restrict__ hpreb,
                                                    float* __restrict__ gsum,
                                                    float* __restrict__ gsumsq,
                                                    int* __restrict__ ctr,
                                                    const float* __restrict__ gamma,
                                                    const float* __restrict__ beta,
                                                    float* __restrict__ scale,
                                                    float* __restrict__ shift, int N) {
    __shared__ float r1[256], r2[256], r3[256], r4[256];
    __shared__ int lastdone;
    int tid = threadIdx.x;
    int cp = tid & 63;
    int rg = tid >> 6;
    float s1l = 0.f, s2l = 0.f, s1h = 0.f, s2h = 0.f;
    for (int r = blockIdx.x * 4 + rg; r < N; r += gridDim.x * 4) {
        uint32 v = hpreb[(size_t)r * 64 + cp];
        float v0 = bflo(v), v1 = bfhi(v);
        s1l += v0; s2l = fmaf(v0, v0, s2l);
        s1h += v1; s2h = fmaf(v1, v1, s2h);
    }
    r1[tid] = s1l; r2[tid] = s2l; r3[tid] = s1h; r4[tid] = s2h;
    __syncthreads();
    if (tid < 64) {
        float t1 = r1[tid] + r1[tid + 64] + r1[tid + 128] + r1[tid + 192];
        float t2 = r2[tid] + r2[tid + 64] + r2[tid + 128] + r2[tid + 192];
        float t3 = r3[tid] + r3[tid + 64] + r3[tid + 128] + r3[tid + 192];
        float t4 = r4[tid] + r4[tid + 64] + r4[tid + 128] + r4[tid + 192];
        atomicAdd(&gsum[tid * 2], t1);
        atomicAdd(&gsumsq[tid * 2], t2);
        atomicAdd(&gsum[tid * 2 + 1], t3);
        atomicAdd(&gsumsq[tid * 2 + 1], t4);
    }
    __threadfence();
    __syncthreads();
    if (tid == 0) lastdone = (atomicAdd(ctr, 1) == (int)gridDim.x - 1);
    __syncthreads();
    if (lastdone && tid < 128) {
        float sv  = atomicAdd(&gsum[tid], 0.f);     // device-scope read
        float sq  = atomicAdd(&gsumsq[tid], 0.f);
        float mu  = sv / (float)N;
        float var = sq / (float)N - mu * mu;
        float sc  = gamma[tid] * rsqrtf(var + EPSV);
        scale[tid] = sc;
        shift[tid] = beta[tid] - mu * sc;
    }
}

// ---------------- Final: BN + ELU + residual (4 channels/thread) ----------------
__global__ __launch_bounds__(256) void final_kernel(const uint2* __restrict__ hpreb2,
                                                    const float4* __restrict__ x4,
                                                    const float* __restrict__ scale,
                                                    const float* __restrict__ shift,
                                                    float4* __restrict__ out4, int total4) {
    int i = blockIdx.x * blockDim.x + threadIdx.x;
    if (i >= total4) return;
    int c0 = (i & 31) * 4;
    uint2 hv = hpreb2[i];
    float4 xv = x4[i];
    float t0 = fmaf(bflo(hv.x), scale[c0],     shift[c0]);
    float t1 = fmaf(bfhi(hv.x), scale[c0 + 1], shift[c0 + 1]);
    float t2 = fmaf(bflo(hv.y), scale[c0 + 2], shift[c0 + 2]);
    float t3 = fmaf(bfhi(hv.y), scale[c0 + 3], shift[c0 + 3]);
    t0 = t0 > 0.f ? t0 : expm1f(t0);
    t1 = t1 > 0.f ? t1 : expm1f(t1);
    t2 = t2 > 0.f ? t2 : expm1f(t2);
    t3 = t3 > 0.f ? t3 : expm1f(t3);
    out4[i] = make_float4(xv.x + t0, xv.y + t1, xv.z + t2, xv.w + t3);
}

extern "C" void kernel_launch(void* const* d_in, const int* in_sizes, int n_in,
                              void* d_out, int out_size, void* d_ws, size_t ws_size,
                              hipStream_t stream) {
    const float* x      = (const float*)d_in[0];
    const int*   src    = (const int*)d_in[1];
    const int*   dst    = (const int*)d_in[2];
    const float* W      = (const float*)d_in[3];
    const float* attn_l = (const float*)d_in[4];
    const float* attn_r = (const float*)d_in[5];
    const float* gamma  = (const float*)d_in[7];
    const float* beta   = (const float*)d_in[8];
    // d_in[6] (bias) cancels exactly in batch-stats BN -> skipped.

    const int N = in_sizes[0] / 128;
    const int E = in_sizes[1];
    const int nbucket = (N + 511) >> BSHIFT;
    const int NG = (N + 63) / 64;
    const int NS = (E + SCHUNK - 1) / SCHUNK;

    char* ws = (char*)d_ws;
    size_t off = 0;
    auto alloc = [&](size_t bytes) -> void* {
        void* p = ws + off;
        off += (bytes + 255) & ~(size_t)255;
        return p;
    };
    uint32* featb  = (uint32*)alloc((size_t)N * 64 * 4);            // 25.6MB bf16x2
    uint32* hpreb  = (uint32*)alloc((size_t)N * 64 * 4);            // 25.6MB bf16x2
    float* el      = (float*)alloc((size_t)N * 8 * 4);
    float* er      = (float*)alloc((size_t)N * 8 * 4);
    int*   pairs   = (int*)alloc((size_t)nbucket * BCAP * 4);       // 8MB packed
    int*   csr     = (int*)alloc((size_t)nbucket * BCAP * 4);       // 8MB
    int*   obeg    = (int*)alloc((size_t)N * 4);
    int*   oend    = (int*)alloc((size_t)N * 4);
    int*   bcur    = (int*)alloc((size_t)nbucket * 4);
    unsigned short* Wtb2 = (unsigned short*)alloc(144 * 128 * 2);   // bf16 [W|WL|WR]^T
    float* gsum    = (float*)alloc(512);
    float* gsumsq  = (float*)alloc(512);
    int*   ctr     = (int*)alloc(256);
    float* scale   = (float*)alloc(512);
    float* shift   = (float*)alloc(512);

    prep_w_kernel<<<10, 256, 0, stream>>>(W, attn_l, attn_r, Wtb2, bcur, gsum, gsumsq, ctr, nbucket);
    fat_kernel<<<NG + NS, 256, 0, stream>>>(x, Wtb2, (uint4*)featb, el, er,
                                            src, dst, bcur, pairs, N, E, nbucket, NG);
    bucket_build_kernel<<<nbucket, 1024, 0, stream>>>(pairs, bcur, csr, obeg, oend, N);
    aggregate_kernel<<<(N + 3) / 4, 256, 0, stream>>>((const uint4*)featb, el, er, obeg, oend, csr,
                                                      (uint4*)hpreb, N);
    stats_kernel<<<256, 256, 0, stream>>>(hpreb, gsum, gsumsq, ctr, gamma, beta, scale, shift, N);
    final_kernel<<<(N * 32 + 255) / 256, 256, 0, stream>>>((const uint2*)hpreb, (const float4*)x,
                                                           scale, shift, (float4*)d_out, N * 32);
}